// Round 2
// baseline (376.700 us; speedup 1.0000x reference)
//
#include <hip/hip_runtime.h>

// LogicDense: out[i,o] = c0[o] + c1[o]*x[i,ia[o]] + c2[o]*x[i,ib[o]] + c3[o]*x[i,ia[o]]*x[i,ib[o]]
// where c[o] = softmax(weight[o,:16]) @ C_table.
// BATCH=4096, IN_DIM=8192, OUT_DIM=16384. All f32.

constexpr int BATCH   = 4096;
constexpr int IN_DIM  = 8192;
constexpr int OUT_DIM = 16384;

// native clang vector types: required by __builtin_nontemporal_load/store
typedef float f32x2 __attribute__((ext_vector_type(2)));

// ---------------- Kernel 1: fold softmax(weight) into 4 poly coefficients ----------------
__global__ __launch_bounds__(256) void coef_kernel(const float* __restrict__ w,
                                                   float4* __restrict__ coef) {
    // constexpr table -> compile-time immediates, zero terms fold away
    constexpr float C[16][4] = {
        {0, 0, 0, 0},  {0, 0, 0, 1},   {0, 1, 0, -1},  {0, 1, 0, 0},
        {0, 0, 1, -1}, {0, 0, 1, 0},   {0, 1, 1, -2},  {0, 1, 1, -1},
        {1, -1, -1, 1},{1, -1, -1, 2}, {1, 0, -1, 0},  {1, 0, -1, 1},
        {1, -1, 0, 0}, {1, -1, 0, 1},  {1, 0, 0, -1},  {1, 0, 0, 0},
    };
    const int o = blockIdx.x * 256 + threadIdx.x;   // grid sized exactly: no guard needed
    const float4* w4 = reinterpret_cast<const float4*>(w) + (size_t)o * 4;
    float v[16];
    float4 t0 = w4[0], t1 = w4[1], t2 = w4[2], t3 = w4[3];
    v[0]=t0.x; v[1]=t0.y; v[2]=t0.z; v[3]=t0.w;
    v[4]=t1.x; v[5]=t1.y; v[6]=t1.z; v[7]=t1.w;
    v[8]=t2.x; v[9]=t2.y; v[10]=t2.z; v[11]=t2.w;
    v[12]=t3.x; v[13]=t3.y; v[14]=t3.z; v[15]=t3.w;

    float m = v[0];
    #pragma unroll
    for (int k = 1; k < 16; ++k) m = fmaxf(m, v[k]);

    float s = 0.f, c0 = 0.f, c1 = 0.f, c2 = 0.f, c3 = 0.f;
    #pragma unroll
    for (int k = 0; k < 16; ++k) {
        float e = __expf(v[k] - m);
        s += e;
        c0 = fmaf(e, C[k][0], c0);
        c1 = fmaf(e, C[k][1], c1);
        c2 = fmaf(e, C[k][2], c2);
        c3 = fmaf(e, C[k][3], c3);
    }
    const float inv = 1.f / s;
    coef[o] = make_float4(c0 * inv, c1 * inv, c2 * inv, c3 * inv);
}

// ---------------- Kernel 2: gather + polynomial, 2 batch rows per block ----------------
// LDS holds TWO x-rows interleaved as float2 -> one ds_read_b64 per gather index
// serves both rows. 64 KB LDS/block, 512 threads -> 2 blocks/CU, 16 waves/CU.
__global__ __launch_bounds__(512) void logic_kernel(
    const float*  __restrict__ x,
    const float4* __restrict__ coef,
    const int*    __restrict__ idx_a,
    const int*    __restrict__ idx_b,
    float*        __restrict__ out)
{
    __shared__ f32x2 xs[IN_DIM];           // xs[i] = { x[row0][i], x[row0+1][i] }  (64 KB)

    const int row0 = blockIdx.x * 2;
    const f32x2* r0 = reinterpret_cast<const f32x2*>(x + (size_t)row0 * IN_DIM);
    const f32x2* r1 = reinterpret_cast<const f32x2*>(x + (size_t)(row0 + 1) * IN_DIM);

    // Stage both rows, interleaved. Writes are lane-contiguous -> conflict-free.
    // Non-temporal: each x row is read exactly once on the whole chip.
    for (int i = threadIdx.x; i < IN_DIM / 2; i += 512) {
        f32x2 a = __builtin_nontemporal_load(&r0[i]);
        f32x2 b = __builtin_nontemporal_load(&r1[i]);
        f32x2 lo = { a.x, b.x };
        f32x2 hi = { a.y, b.y };
        xs[2 * i]     = lo;
        xs[2 * i + 1] = hi;
    }
    __syncthreads();

    float* out0 = out + (size_t)row0 * OUT_DIM;
    float* out1 = out0 + OUT_DIM;

    // 32 iterations; unroll 4 batches the idx/coef loads (L2-resident, ~200cy) for ILP.
    #pragma unroll 4
    for (int c = 0; c < OUT_DIM / 512; ++c) {
        const int o  = c * 512 + threadIdx.x;
        const int ia = idx_a[o];
        const int ib = idx_b[o];
        const float4 cf = coef[o];
        const f32x2 va = xs[ia];           // {row0 val, row1 val}
        const f32x2 vb = xs[ib];
        float y0 = fmaf(cf.w, va.x * vb.x, fmaf(cf.z, vb.x, fmaf(cf.y, va.x, cf.x)));
        float y1 = fmaf(cf.w, va.y * vb.y, fmaf(cf.z, vb.y, fmaf(cf.y, va.y, cf.x)));
        __builtin_nontemporal_store(y0, &out0[o]);   // streamed, never re-read
        __builtin_nontemporal_store(y1, &out1[o]);
    }
}

extern "C" void kernel_launch(void* const* d_in, const int* in_sizes, int n_in,
                              void* d_out, int out_size, void* d_ws, size_t ws_size,
                              hipStream_t stream) {
    const float* x      = (const float*)d_in[0];   // (4096, 8192) f32
    const float* weight = (const float*)d_in[1];   // (16384, 16) f32
    const int*   idx_a  = (const int*)d_in[2];     // (16384,) i32
    const int*   idx_b  = (const int*)d_in[3];     // (16384,) i32
    float*       out    = (float*)d_out;           // (4096, 16384) f32
    float4*      coef   = (float4*)d_ws;           // 16384 * 16 B = 256 KB scratch

    coef_kernel<<<OUT_DIM / 256, 256, 0, stream>>>(weight, coef);
    logic_kernel<<<BATCH / 2, 512, 0, stream>>>(x, coef, idx_a, idx_b, out);
}